// Round 5
// baseline (374.233 us; speedup 1.0000x reference)
//
#include <hip/hip_runtime.h>

#define K 5
#define D 128
#define BLOCK 256
#define NBLOCKS 1024

typedef float vf4 __attribute__((ext_vector_type(4)));

// Insert (sim, idx) into a descending-sorted top-K list held in registers.
__device__ __forceinline__ void insert_top(float sim, int idx, float bv[K], int bi[K]) {
    if (sim > bv[K - 1]) {
        bv[K - 1] = sim;
        bi[K - 1] = idx;
#pragma unroll
        for (int j = K - 1; j > 0; --j) {
            if (bv[j] > bv[j - 1]) {
                float tv = bv[j]; bv[j] = bv[j - 1]; bv[j - 1] = tv;
                int   ti = bi[j]; bi[j] = bi[j - 1]; bi[j - 1] = ti;
            }
        }
    }
}

// Fused kernel: streaming cosine-sim scan (8 lanes/row, 16 rows = 8 KiB per
// wave-iteration, nontemporal loads) + per-block top-K -> candidates in d_ws.
// Last finished block (device-scope atomic ticket) merges all candidates and
// writes the global top-K. Ticket is zeroed by a captured memset per launch.
extern "C" __global__ void __launch_bounds__(BLOCK)
cossim_topk_fused(const float* __restrict__ q, const float* __restrict__ M, int N,
                  float* __restrict__ cand_v, int* __restrict__ cand_i,
                  int* __restrict__ ticket, float* __restrict__ out) {
    const int tid   = threadIdx.x;
    const int lane  = tid & 63;
    const int wib   = tid >> 6;                        // wave index in block (0..3)
    const int wid   = blockIdx.x * (BLOCK / 64) + wib; // global wave id
    const int nwave = gridDim.x * (BLOCK / 64);
    const int rsub  = lane >> 3;                       // row sub-index (0..7)
    const int chunk = lane & 7;                        // column chunk (0..7)

    const vf4* __restrict__ Mv = reinterpret_cast<const vf4*>(M);
    const float4* __restrict__ qf4 = reinterpret_cast<const float4*>(q);

    // Lane's q fragment: float4 indices {chunk, chunk+8, chunk+16, chunk+24}.
    float4 qf[4];
#pragma unroll
    for (int j = 0; j < 4; ++j) qf[j] = qf4[chunk + j * 8];

    // ||q||^2: per-lane partial, reduced over the 8-lane group (xor 1,2,4).
    float q2 = 0.f;
#pragma unroll
    for (int j = 0; j < 4; ++j)
        q2 = fmaf(qf[j].x, qf[j].x, fmaf(qf[j].y, qf[j].y,
             fmaf(qf[j].z, qf[j].z, fmaf(qf[j].w, qf[j].w, q2))));
#pragma unroll
    for (int m = 1; m <= 4; m <<= 1) q2 += __shfl_xor(q2, m);
    const float qn = sqrtf(q2);

    float bv[K]; int bi[K];
#pragma unroll
    for (int j = 0; j < K; ++j) { bv[j] = -3.0e38f; bi[j] = 0; }

    const int stride = nwave * 16;
    for (int base = wid * 16; base < N; base += stride) {
        const int rowA = base + rsub;
        const int rowB = base + 8 + rsub;
        const int rcA  = rowA < N ? rowA : N - 1;
        const int rcB  = rowB < N ? rowB : N - 1;
        const size_t rbA = (size_t)rcA * (D / 4);
        const size_t rbB = (size_t)rcB * (D / 4);

        // Issue all 8 nontemporal loads (8 KiB/wave in flight).
        vf4 a[4], b[4];
#pragma unroll
        for (int j = 0; j < 4; ++j) a[j] = __builtin_nontemporal_load(&Mv[rbA + chunk + j * 8]);
#pragma unroll
        for (int j = 0; j < 4; ++j) b[j] = __builtin_nontemporal_load(&Mv[rbB + chunk + j * 8]);

        // Half A
        {
            float dot = 0.f, ss = 0.f;
#pragma unroll
            for (int j = 0; j < 4; ++j) {
                dot = fmaf(a[j].x, qf[j].x, fmaf(a[j].y, qf[j].y,
                      fmaf(a[j].z, qf[j].z, fmaf(a[j].w, qf[j].w, dot))));
                ss  = fmaf(a[j].x, a[j].x,  fmaf(a[j].y, a[j].y,
                      fmaf(a[j].z, a[j].z,  fmaf(a[j].w, a[j].w, ss))));
            }
#pragma unroll
            for (int m = 1; m <= 4; m <<= 1) { dot += __shfl_xor(dot, m); ss += __shfl_xor(ss, m); }
            const float sim = dot / fmaxf(qn * sqrtf(ss), 1e-8f);
            if (rowA < N) insert_top(sim, rowA, bv, bi);
        }
        // Half B
        {
            float dot = 0.f, ss = 0.f;
#pragma unroll
            for (int j = 0; j < 4; ++j) {
                dot = fmaf(b[j].x, qf[j].x, fmaf(b[j].y, qf[j].y,
                      fmaf(b[j].z, qf[j].z, fmaf(b[j].w, qf[j].w, dot))));
                ss  = fmaf(b[j].x, b[j].x,  fmaf(b[j].y, b[j].y,
                      fmaf(b[j].z, b[j].z,  fmaf(b[j].w, b[j].w, ss))));
            }
#pragma unroll
            for (int m = 1; m <= 4; m <<= 1) { dot += __shfl_xor(dot, m); ss += __shfl_xor(ss, m); }
            const float sim = dot / fmaxf(qn * sqrtf(ss), 1e-8f);
            if (rowB < N) insert_top(sim, rowB, bv, bi);
        }
    }

    // Cross-group merge within the wave (lists identical inside each 8-lane
    // group): xor 8,16,32 butterfly of K-lists.
#pragma unroll
    for (int m = 8; m <= 32; m <<= 1) {
        float ov[K]; int oi[K];
#pragma unroll
        for (int j = 0; j < K; ++j) { ov[j] = __shfl_xor(bv[j], m); oi[j] = __shfl_xor(bi[j], m); }
#pragma unroll
        for (int j = 0; j < K; ++j) insert_top(ov[j], oi[j], bv, bi);
    }

    // Merge the block's 4 wave-lists via LDS; leader writes 5 candidates.
    __shared__ float sv[(BLOCK / 64) * K];
    __shared__ int   si[(BLOCK / 64) * K];
    if (lane == 0) {
#pragma unroll
        for (int j = 0; j < K; ++j) { sv[wib * K + j] = bv[j]; si[wib * K + j] = bi[j]; }
    }
    __syncthreads();
    if (tid == 0) {
        float mv[K]; int mi[K];
#pragma unroll
        for (int j = 0; j < K; ++j) { mv[j] = sv[j]; mi[j] = si[j]; }
        for (int c = K; c < (BLOCK / 64) * K; ++c) insert_top(sv[c], si[c], mv, mi);
#pragma unroll
        for (int j = 0; j < K; ++j) {
            cand_v[blockIdx.x * K + j] = mv[j];
            cand_i[blockIdx.x * K + j] = mi[j];
        }
    }

    // ---- last-block-done final merge ----
    __shared__ int is_last;
    __threadfence();                       // release candidate writes (device scope)
    if (tid == 0) {
        const int prev = atomicAdd(ticket, 1);   // device-scope on CDNA
        is_last = (prev == (int)gridDim.x - 1);
    }
    __syncthreads();
    if (!is_last) return;

    __threadfence();                       // acquire side
    const volatile float* vv = cand_v;
    const volatile int*   vi = cand_i;
    const int ncand = (int)gridDim.x * K;

    float fv[K]; int fi[K];
#pragma unroll
    for (int j = 0; j < K; ++j) { fv[j] = -3.0e38f; fi[j] = 0; }
    for (int c = tid; c < ncand; c += BLOCK) insert_top(vv[c], vi[c], fv, fi);

    // In-wave butterfly merge: every lane ends with the wave's top-K.
#pragma unroll
    for (int m = 1; m <= 32; m <<= 1) {
        float ov[K]; int oi[K];
#pragma unroll
        for (int j = 0; j < K; ++j) { ov[j] = __shfl_xor(fv[j], m); oi[j] = __shfl_xor(fi[j], m); }
#pragma unroll
        for (int j = 0; j < K; ++j) insert_top(ov[j], oi[j], fv, fi);
    }

    __syncthreads();                       // reuse sv/si safely
    if (lane == 0) {
#pragma unroll
        for (int j = 0; j < K; ++j) { sv[wib * K + j] = fv[j]; si[wib * K + j] = fi[j]; }
    }
    __syncthreads();
    if (tid == 0) {
        float mv[K]; int mi[K];
#pragma unroll
        for (int j = 0; j < K; ++j) { mv[j] = sv[j]; mi[j] = si[j]; }
        for (int c = K; c < (BLOCK / 64) * K; ++c) insert_top(sv[c], si[c], mv, mi);
        // Output layout: [top_vals (K floats)] [top_idx (K, written as float)]
#pragma unroll
        for (int j = 0; j < K; ++j) {
            out[j]     = mv[j];
            out[K + j] = (float)mi[j];
        }
    }
}

extern "C" void kernel_launch(void* const* d_in, const int* in_sizes, int n_in,
                              void* d_out, int out_size, void* d_ws, size_t ws_size,
                              hipStream_t stream) {
    const float* q = (const float*)d_in[0];   // [1, 128]
    const float* M = (const float*)d_in[1];   // [N, 128]
    const int N = in_sizes[1] / D;

    int nb = NBLOCKS;
    const size_t per_blk = K * (sizeof(float) + sizeof(int));
    if ((size_t)nb * per_blk + sizeof(int) > ws_size)
        nb = (int)((ws_size - sizeof(int)) / per_blk);

    float* cand_v = (float*)d_ws;
    int*   cand_i = (int*)((char*)d_ws + (size_t)nb * K * sizeof(float));
    int*   ticket = (int*)((char*)d_ws + (size_t)nb * per_blk);

    // Zero the ticket (captured as a memset node; deterministic per replay).
    hipMemsetAsync(ticket, 0, sizeof(int), stream);

    hipLaunchKernelGGL(cossim_topk_fused, dim3(nb), dim3(BLOCK), 0, stream,
                       q, M, N, cand_v, cand_i, ticket, (float*)d_out);
}

// Round 6
// 195.224 us; speedup vs baseline: 1.9169x; 1.9169x over previous
//
#include <hip/hip_runtime.h>

#define K 5
#define D 128
#define BLOCK 256
#define NBLOCKS 2048

typedef float vf4 __attribute__((ext_vector_type(4)));

// Insert (sim, idx) into a descending-sorted top-K list held in registers.
__device__ __forceinline__ void insert_top(float sim, int idx, float bv[K], int bi[K]) {
    if (sim > bv[K - 1]) {
        bv[K - 1] = sim;
        bi[K - 1] = idx;
#pragma unroll
        for (int j = K - 1; j > 0; --j) {
            if (bv[j] > bv[j - 1]) {
                float tv = bv[j]; bv[j] = bv[j - 1]; bv[j - 1] = tv;
                int   ti = bi[j]; bi[j] = bi[j - 1]; bi[j - 1] = ti;
            }
        }
    }
}

// Fused: streaming cosine-sim scan (8 lanes/row, 16 rows = 8 KiB per
// wave-iteration, nontemporal loads) + per-block top-K. Candidates are
// published with agent-scope RELAXED atomic exchanges (performed at the
// device coherent point -> no fences / no buffer_wbl2 needed); completion is
// forced by consuming the atomic return values before the ticket fetch_add.
// The last block reads candidates back with agent-scope relaxed atomic loads.
extern "C" __global__ void __launch_bounds__(BLOCK)
cossim_topk_fused(const float* __restrict__ q, const float* __restrict__ M, int N,
                  unsigned* __restrict__ cand_v, unsigned* __restrict__ cand_i,
                  int* __restrict__ ticket, float* __restrict__ out) {
    const int tid   = threadIdx.x;
    const int lane  = tid & 63;
    const int wib   = tid >> 6;                        // wave index in block (0..3)
    const int wid   = blockIdx.x * (BLOCK / 64) + wib; // global wave id
    const int nwave = gridDim.x * (BLOCK / 64);
    const int rsub  = lane >> 3;                       // row sub-index (0..7)
    const int chunk = lane & 7;                        // column chunk (0..7)

    const vf4* __restrict__ Mv = reinterpret_cast<const vf4*>(M);
    const float4* __restrict__ qf4 = reinterpret_cast<const float4*>(q);

    // Lane's q fragment: float4 indices {chunk, chunk+8, chunk+16, chunk+24}.
    float4 qf[4];
#pragma unroll
    for (int j = 0; j < 4; ++j) qf[j] = qf4[chunk + j * 8];

    // ||q||^2: per-lane partial, reduced over the 8-lane group (xor 1,2,4).
    float q2 = 0.f;
#pragma unroll
    for (int j = 0; j < 4; ++j)
        q2 = fmaf(qf[j].x, qf[j].x, fmaf(qf[j].y, qf[j].y,
             fmaf(qf[j].z, qf[j].z, fmaf(qf[j].w, qf[j].w, q2))));
#pragma unroll
    for (int m = 1; m <= 4; m <<= 1) q2 += __shfl_xor(q2, m);
    const float qn = sqrtf(q2);

    float bv[K]; int bi[K];
#pragma unroll
    for (int j = 0; j < K; ++j) { bv[j] = -3.0e38f; bi[j] = 0; }

    const int stride = nwave * 16;
    for (int base = wid * 16; base < N; base += stride) {
        const int rowA = base + rsub;
        const int rowB = base + 8 + rsub;
        const int rcA  = rowA < N ? rowA : N - 1;
        const int rcB  = rowB < N ? rowB : N - 1;
        const size_t rbA = (size_t)rcA * (D / 4);
        const size_t rbB = (size_t)rcB * (D / 4);

        // Issue all 8 nontemporal loads (8 KiB/wave in flight).
        vf4 a[4], b[4];
#pragma unroll
        for (int j = 0; j < 4; ++j) a[j] = __builtin_nontemporal_load(&Mv[rbA + chunk + j * 8]);
#pragma unroll
        for (int j = 0; j < 4; ++j) b[j] = __builtin_nontemporal_load(&Mv[rbB + chunk + j * 8]);

        // Half A
        {
            float dot = 0.f, ss = 0.f;
#pragma unroll
            for (int j = 0; j < 4; ++j) {
                dot = fmaf(a[j].x, qf[j].x, fmaf(a[j].y, qf[j].y,
                      fmaf(a[j].z, qf[j].z, fmaf(a[j].w, qf[j].w, dot))));
                ss  = fmaf(a[j].x, a[j].x,  fmaf(a[j].y, a[j].y,
                      fmaf(a[j].z, a[j].z,  fmaf(a[j].w, a[j].w, ss))));
            }
#pragma unroll
            for (int m = 1; m <= 4; m <<= 1) { dot += __shfl_xor(dot, m); ss += __shfl_xor(ss, m); }
            const float sim = dot / fmaxf(qn * sqrtf(ss), 1e-8f);
            if (rowA < N) insert_top(sim, rowA, bv, bi);
        }
        // Half B
        {
            float dot = 0.f, ss = 0.f;
#pragma unroll
            for (int j = 0; j < 4; ++j) {
                dot = fmaf(b[j].x, qf[j].x, fmaf(b[j].y, qf[j].y,
                      fmaf(b[j].z, qf[j].z, fmaf(b[j].w, qf[j].w, dot))));
                ss  = fmaf(b[j].x, b[j].x,  fmaf(b[j].y, b[j].y,
                      fmaf(b[j].z, b[j].z,  fmaf(b[j].w, b[j].w, ss))));
            }
#pragma unroll
            for (int m = 1; m <= 4; m <<= 1) { dot += __shfl_xor(dot, m); ss += __shfl_xor(ss, m); }
            const float sim = dot / fmaxf(qn * sqrtf(ss), 1e-8f);
            if (rowB < N) insert_top(sim, rowB, bv, bi);
        }
    }

    // Cross-group merge within the wave (lists identical inside each 8-lane
    // group): xor 8,16,32 butterfly of K-lists.
#pragma unroll
    for (int m = 8; m <= 32; m <<= 1) {
        float ov[K]; int oi[K];
#pragma unroll
        for (int j = 0; j < K; ++j) { ov[j] = __shfl_xor(bv[j], m); oi[j] = __shfl_xor(bi[j], m); }
#pragma unroll
        for (int j = 0; j < K; ++j) insert_top(ov[j], oi[j], bv, bi);
    }

    // Merge the block's 4 wave-lists via LDS; leader publishes 5 candidates.
    __shared__ float sv[(BLOCK / 64) * K];
    __shared__ int   si[(BLOCK / 64) * K];
    __shared__ int   last_flag;
    if (lane == 0) {
#pragma unroll
        for (int j = 0; j < K; ++j) { sv[wib * K + j] = bv[j]; si[wib * K + j] = bi[j]; }
    }
    __syncthreads();
    if (tid == 0) {
        float mv[K]; int mi[K];
#pragma unroll
        for (int j = 0; j < K; ++j) { mv[j] = sv[j]; mi[j] = si[j]; }
        for (int c = K; c < (BLOCK / 64) * K; ++c) insert_top(sv[c], si[c], mv, mi);

        // Publish via agent-scope relaxed atomic exchange: performed at the
        // device coherent point, no cache-maintenance (no wbl2/inv) emitted.
        unsigned keep = 0;
#pragma unroll
        for (int j = 0; j < K; ++j) {
            keep += __hip_atomic_exchange(&cand_v[blockIdx.x * K + j],
                                          __float_as_uint(mv[j]),
                                          __ATOMIC_RELAXED, __HIP_MEMORY_SCOPE_AGENT);
            keep += __hip_atomic_exchange(&cand_i[blockIdx.x * K + j],
                                          (unsigned)mi[j],
                                          __ATOMIC_RELAXED, __HIP_MEMORY_SCOPE_AGENT);
        }
        // Consume returns -> compiler emits s_waitcnt vmcnt(0): all exchanges
        // globally performed before the ticket bump below issues.
        asm volatile("" : : "v"(keep) : "memory");

        const int prev = __hip_atomic_fetch_add(ticket, 1, __ATOMIC_RELAXED,
                                                __HIP_MEMORY_SCOPE_AGENT);
        last_flag = (prev == (int)gridDim.x - 1);
    }
    __syncthreads();
    if (!last_flag) return;

    // ---- last block: final merge via coherent-point reads ----
    const int ncand = (int)gridDim.x * K;
    float fv[K]; int fi[K];
#pragma unroll
    for (int j = 0; j < K; ++j) { fv[j] = -3.0e38f; fi[j] = 0; }
    for (int c = tid; c < ncand; c += BLOCK) {
        const float v = __uint_as_float(__hip_atomic_load(&cand_v[c], __ATOMIC_RELAXED,
                                                          __HIP_MEMORY_SCOPE_AGENT));
        const int   i = (int)__hip_atomic_load(&cand_i[c], __ATOMIC_RELAXED,
                                               __HIP_MEMORY_SCOPE_AGENT);
        insert_top(v, i, fv, fi);
    }

    // In-wave butterfly merge: every lane ends with the wave's top-K.
#pragma unroll
    for (int m = 1; m <= 32; m <<= 1) {
        float ov[K]; int oi[K];
#pragma unroll
        for (int j = 0; j < K; ++j) { ov[j] = __shfl_xor(fv[j], m); oi[j] = __shfl_xor(fi[j], m); }
#pragma unroll
        for (int j = 0; j < K; ++j) insert_top(ov[j], oi[j], fv, fi);
    }

    if (lane == 0) {
#pragma unroll
        for (int j = 0; j < K; ++j) { sv[wib * K + j] = fv[j]; si[wib * K + j] = fi[j]; }
    }
    __syncthreads();
    if (tid == 0) {
        float mv[K]; int mi[K];
#pragma unroll
        for (int j = 0; j < K; ++j) { mv[j] = sv[j]; mi[j] = si[j]; }
        for (int c = K; c < (BLOCK / 64) * K; ++c) insert_top(sv[c], si[c], mv, mi);
        // Output layout: [top_vals (K floats)] [top_idx (K, written as float)]
#pragma unroll
        for (int j = 0; j < K; ++j) {
            out[j]     = mv[j];
            out[K + j] = (float)mi[j];
        }
    }
}

extern "C" void kernel_launch(void* const* d_in, const int* in_sizes, int n_in,
                              void* d_out, int out_size, void* d_ws, size_t ws_size,
                              hipStream_t stream) {
    const float* q = (const float*)d_in[0];   // [1, 128]
    const float* M = (const float*)d_in[1];   // [N, 128]
    const int N = in_sizes[1] / D;

    int nb = NBLOCKS;
    const size_t per_blk = K * 2 * sizeof(unsigned);
    if ((size_t)nb * per_blk + sizeof(int) > ws_size)
        nb = (int)((ws_size - sizeof(int)) / per_blk);

    unsigned* cand_v = (unsigned*)d_ws;
    unsigned* cand_i = (unsigned*)((char*)d_ws + (size_t)nb * K * sizeof(unsigned));
    int*      ticket = (int*)((char*)d_ws + (size_t)nb * per_blk);

    // Zero the ticket (captured as a memset node; deterministic per replay).
    hipMemsetAsync(ticket, 0, sizeof(int), stream);

    hipLaunchKernelGGL(cossim_topk_fused, dim3(nb), dim3(BLOCK), 0, stream,
                       q, M, N, cand_v, cand_i, ticket, (float*)d_out);
}

// Round 7
// 167.941 us; speedup vs baseline: 2.2284x; 1.1625x over previous
//
#include <hip/hip_runtime.h>

#define K 5
#define D 128
#define BLOCK 256
#define NBLOCKS 1024
#define P2T 256                    // pass2 threads
#define CPT (NBLOCKS * K / P2T)    // candidates per pass2 thread (20)

typedef float vf4 __attribute__((ext_vector_type(4)));

// Insert (sim, idx) into a descending-sorted top-K list held in registers.
__device__ __forceinline__ void insert_top(float sim, int idx, float bv[K], int bi[K]) {
    if (sim > bv[K - 1]) {
        bv[K - 1] = sim;
        bi[K - 1] = idx;
#pragma unroll
        for (int j = K - 1; j > 0; --j) {
            if (bv[j] > bv[j - 1]) {
                float tv = bv[j]; bv[j] = bv[j - 1]; bv[j - 1] = tv;
                int   ti = bi[j]; bi[j] = bi[j - 1]; bi[j - 1] = ti;
            }
        }
    }
}

// Pass 1: 8 lanes per row, 16 rows (8 KiB) per wave-iteration, 2-deep pipeline:
// all 8 nontemporal loads issued up front, then the two 8-row halves computed
// back-to-back so the second half's loads stay in flight under the first
// half's shuffle/sqrt/div chain. 1024 blocks -> 4096 waves -> 30.5 iters/wave
// (1.6% straggler tail vs 4.8% at 2048 blocks).
extern "C" __global__ void __launch_bounds__(BLOCK)
cossim_topk_pass1(const float* __restrict__ q, const float* __restrict__ M, int N,
                  float* __restrict__ cand_v, int* __restrict__ cand_i) {
    const int tid   = threadIdx.x;
    const int lane  = tid & 63;
    const int wib   = tid >> 6;                        // wave index in block (0..3)
    const int wid   = blockIdx.x * (BLOCK / 64) + wib; // global wave id
    const int nwave = gridDim.x * (BLOCK / 64);
    const int rsub  = lane >> 3;                       // row sub-index (0..7)
    const int chunk = lane & 7;                        // column chunk (0..7)

    const vf4* __restrict__ Mv = reinterpret_cast<const vf4*>(M);
    const float4* __restrict__ qf4 = reinterpret_cast<const float4*>(q);

    // Lane's q fragment: float4 indices {chunk, chunk+8, chunk+16, chunk+24}.
    float4 qf[4];
#pragma unroll
    for (int j = 0; j < 4; ++j) qf[j] = qf4[chunk + j * 8];

    // ||q||^2: per-lane partial, reduced over the 8-lane group (xor 1,2,4).
    float q2 = 0.f;
#pragma unroll
    for (int j = 0; j < 4; ++j)
        q2 = fmaf(qf[j].x, qf[j].x, fmaf(qf[j].y, qf[j].y,
             fmaf(qf[j].z, qf[j].z, fmaf(qf[j].w, qf[j].w, q2))));
#pragma unroll
    for (int m = 1; m <= 4; m <<= 1) q2 += __shfl_xor(q2, m);
    const float qn = sqrtf(q2);

    float bv[K]; int bi[K];
#pragma unroll
    for (int j = 0; j < K; ++j) { bv[j] = -3.0e38f; bi[j] = 0; }

    const int stride = nwave * 16;
    for (int base = wid * 16; base < N; base += stride) {
        const int rowA = base + rsub;
        const int rowB = base + 8 + rsub;
        const int rcA  = rowA < N ? rowA : N - 1;
        const int rcB  = rowB < N ? rowB : N - 1;
        const size_t rbA = (size_t)rcA * (D / 4);
        const size_t rbB = (size_t)rcB * (D / 4);

        // Issue all 8 nontemporal loads (8 KiB/wave in flight).
        vf4 a[4], b[4];
#pragma unroll
        for (int j = 0; j < 4; ++j) a[j] = __builtin_nontemporal_load(&Mv[rbA + chunk + j * 8]);
#pragma unroll
        for (int j = 0; j < 4; ++j) b[j] = __builtin_nontemporal_load(&Mv[rbB + chunk + j * 8]);

        // Half A
        {
            float dot = 0.f, ss = 0.f;
#pragma unroll
            for (int j = 0; j < 4; ++j) {
                dot = fmaf(a[j].x, qf[j].x, fmaf(a[j].y, qf[j].y,
                      fmaf(a[j].z, qf[j].z, fmaf(a[j].w, qf[j].w, dot))));
                ss  = fmaf(a[j].x, a[j].x,  fmaf(a[j].y, a[j].y,
                      fmaf(a[j].z, a[j].z,  fmaf(a[j].w, a[j].w, ss))));
            }
#pragma unroll
            for (int m = 1; m <= 4; m <<= 1) { dot += __shfl_xor(dot, m); ss += __shfl_xor(ss, m); }
            const float sim = dot / fmaxf(qn * sqrtf(ss), 1e-8f);
            if (rowA < N) insert_top(sim, rowA, bv, bi);
        }
        // Half B
        {
            float dot = 0.f, ss = 0.f;
#pragma unroll
            for (int j = 0; j < 4; ++j) {
                dot = fmaf(b[j].x, qf[j].x, fmaf(b[j].y, qf[j].y,
                      fmaf(b[j].z, qf[j].z, fmaf(b[j].w, qf[j].w, dot))));
                ss  = fmaf(b[j].x, b[j].x,  fmaf(b[j].y, b[j].y,
                      fmaf(b[j].z, b[j].z,  fmaf(b[j].w, b[j].w, ss))));
            }
#pragma unroll
            for (int m = 1; m <= 4; m <<= 1) { dot += __shfl_xor(dot, m); ss += __shfl_xor(ss, m); }
            const float sim = dot / fmaxf(qn * sqrtf(ss), 1e-8f);
            if (rowB < N) insert_top(sim, rowB, bv, bi);
        }
    }

    // Cross-group merge within the wave (lists identical inside each 8-lane
    // group): xor 8,16,32 butterfly of K-lists.
#pragma unroll
    for (int m = 8; m <= 32; m <<= 1) {
        float ov[K]; int oi[K];
#pragma unroll
        for (int j = 0; j < K; ++j) { ov[j] = __shfl_xor(bv[j], m); oi[j] = __shfl_xor(bi[j], m); }
#pragma unroll
        for (int j = 0; j < K; ++j) insert_top(ov[j], oi[j], bv, bi);
    }

    // Merge the block's 4 wave-lists via LDS.
    __shared__ float sv[(BLOCK / 64) * K];
    __shared__ int   si[(BLOCK / 64) * K];
    if (lane == 0) {
#pragma unroll
        for (int j = 0; j < K; ++j) { sv[wib * K + j] = bv[j]; si[wib * K + j] = bi[j]; }
    }
    __syncthreads();
    if (tid == 0) {
        float mv[K]; int mi[K];
#pragma unroll
        for (int j = 0; j < K; ++j) { mv[j] = sv[j]; mi[j] = si[j]; }
        for (int c = K; c < (BLOCK / 64) * K; ++c) insert_top(sv[c], si[c], mv, mi);
#pragma unroll
        for (int j = 0; j < K; ++j) {
            cand_v[blockIdx.x * K + j] = mv[j];
            cand_i[blockIdx.x * K + j] = mi[j];
        }
    }
}

// Pass 2: one 256-thread block reduces nb*K candidates to global top-K.
// Load phase first (all of a thread's candidates in flight -> full MLP),
// then insert phase, then butterfly + LDS merge.
extern "C" __global__ void __launch_bounds__(P2T)
cossim_topk_pass2(const float* __restrict__ cand_v, const int* __restrict__ cand_i,
                  int ncand, float* __restrict__ out) {
    const int tid = threadIdx.x;
    float bv[K]; int bi[K];
#pragma unroll
    for (int j = 0; j < K; ++j) { bv[j] = -3.0e38f; bi[j] = 0; }

    if (ncand == NBLOCKS * K) {
        // Fast path: compile-time trip count, loads hoisted before inserts.
        float lv[CPT]; int li[CPT];
#pragma unroll
        for (int j = 0; j < CPT; ++j) {
            lv[j] = cand_v[tid + j * P2T];
            li[j] = cand_i[tid + j * P2T];
        }
#pragma unroll
        for (int j = 0; j < CPT; ++j) insert_top(lv[j], li[j], bv, bi);
    } else {
        for (int c = tid; c < ncand; c += P2T) insert_top(cand_v[c], cand_i[c], bv, bi);
    }

    // In-wave butterfly merge: after 6 steps every lane holds the wave's top-K.
#pragma unroll
    for (int m = 1; m <= 32; m <<= 1) {
        float ov[K]; int oi[K];
#pragma unroll
        for (int j = 0; j < K; ++j) { ov[j] = __shfl_xor(bv[j], m); oi[j] = __shfl_xor(bi[j], m); }
#pragma unroll
        for (int j = 0; j < K; ++j) insert_top(ov[j], oi[j], bv, bi);
    }

    __shared__ float sv[(P2T / 64) * K];
    __shared__ int   si[(P2T / 64) * K];
    if ((tid & 63) == 0) {
        const int w = tid >> 6;
#pragma unroll
        for (int j = 0; j < K; ++j) { sv[w * K + j] = bv[j]; si[w * K + j] = bi[j]; }
    }
    __syncthreads();

    if (tid == 0) {
        float mv[K]; int mi[K];
#pragma unroll
        for (int j = 0; j < K; ++j) { mv[j] = sv[j]; mi[j] = si[j]; }
        for (int c = K; c < (P2T / 64) * K; ++c) insert_top(sv[c], si[c], mv, mi);
        // Output layout: [top_vals (K floats)] [top_idx (K, written as float)]
#pragma unroll
        for (int j = 0; j < K; ++j) {
            out[j]     = mv[j];
            out[K + j] = (float)mi[j];
        }
    }
}

extern "C" void kernel_launch(void* const* d_in, const int* in_sizes, int n_in,
                              void* d_out, int out_size, void* d_ws, size_t ws_size,
                              hipStream_t stream) {
    const float* q = (const float*)d_in[0];   // [1, 128]
    const float* M = (const float*)d_in[1];   // [N, 128]
    const int N = in_sizes[1] / D;

    int nb = NBLOCKS;
    const size_t per_blk = K * (sizeof(float) + sizeof(int));
    if ((size_t)nb * per_blk > ws_size)
        nb = (int)(ws_size / per_blk);

    float* cand_v = (float*)d_ws;
    int*   cand_i = (int*)((char*)d_ws + (size_t)nb * K * sizeof(float));

    hipLaunchKernelGGL(cossim_topk_pass1, dim3(nb), dim3(BLOCK), 0, stream,
                       q, M, N, cand_v, cand_i);
    hipLaunchKernelGGL(cossim_topk_pass2, dim3(1), dim3(P2T), 0, stream,
                       cand_v, cand_i, nb * K, (float*)d_out);
}